// Round 10
// baseline (241.318 us; speedup 1.0000x reference)
//
#include <hip/hip_runtime.h>
#include <hip/hip_bf16.h>
#include <math.h>

// CausalSelfAttention  B=4, S=2048, D=1024, H=16, HD=64
// R16: attn softmax-VALU cuts (R15 counters: VALUBusy 48% = top pipe):
//   (1) mask fast path: 4 L1 loads + __all -> wave-uniform skip of all bias
//       adds; mb[] LDS buffer removed entirely. Slow path (any masked key)
//       loads per-element mask from global (correct, unused in this bench).
//   (2) v_perm_b32 pair pack (bit-identical to f2bfu_rn pack, fewer ops).
//   qkv (R15 2-phase ring-3), convert, combine unchanged.

#define B_ 4
#define S_ 2048
#define D_ 1024
#define H_ 16
#define HD_ 64
#define M_ (B_ * S_)   // 8192

typedef unsigned short u16;
typedef unsigned int u32;
typedef __attribute__((ext_vector_type(4))) float f32x4;
typedef __attribute__((ext_vector_type(8))) short bf16x8;   // 8 bf16 in 4 VGPRs

__device__ __forceinline__ u16 f2bfu_rn(float x) {
    u32 u = __builtin_bit_cast(u32, x);
    return (u16)((u + 0x8000u) >> 16);
}

// pack two f32 -> (bf16(hi)<<16)|bf16(lo), bit-identical to f2bfu_rn pairs:
// a' = bits(lo)+0x8000, b' = bits(hi)+0x8000; take hi16 of each via v_perm.
__device__ __forceinline__ u32 pack_bf16(float lo, float hi) {
    u32 a = __builtin_bit_cast(u32, lo) + 0x8000u;
    u32 b = __builtin_bit_cast(u32, hi) + 0x8000u;
    return __builtin_amdgcn_perm(b, a, 0x07060302u);  // {b.b3,b.b2,a.b3,a.b2}
}

__device__ __forceinline__ void gl2lds16(const void* g, void* l) {
    __builtin_amdgcn_global_load_lds(
        (const __attribute__((address_space(1))) u32*)g,
        (__attribute__((address_space(3))) u32*)l, 16, 0, 0);
}

// ---------------------------------------------------------------------------
// fp32 -> bf16 conversion, 8 elems/thread
// ---------------------------------------------------------------------------
#define XN  8388608u    // 8192*1024
#define WN  1048576u    // 1024*1024
__global__ __launch_bounds__(256) void convert_bf16(
    const float* __restrict__ X,  const float* __restrict__ Wq,
    const float* __restrict__ Wk, const float* __restrict__ Wv,
    u16* __restrict__ Xb, u16* __restrict__ Wqb,
    u16* __restrict__ Wkb, u16* __restrict__ Wvb)
{
    size_t idx = ((size_t)blockIdx.x * 256 + threadIdx.x) * 8;
    const float* src; u16* dst; size_t off;
    if (idx < XN)                { src = X;  dst = Xb;  off = idx; }
    else if (idx < XN + WN)      { src = Wq; dst = Wqb; off = idx - XN; }
    else if (idx < XN + 2 * WN)  { src = Wk; dst = Wkb; off = idx - XN - WN; }
    else                         { src = Wv; dst = Wvb; off = idx - XN - 2 * WN; }
    float4 a = *(const float4*)(src + off);
    float4 b = *(const float4*)(src + off + 4);
    uint4 o;
    o.x = (u32)f2bfu_rn(a.x) | ((u32)f2bfu_rn(a.y) << 16);
    o.y = (u32)f2bfu_rn(a.z) | ((u32)f2bfu_rn(a.w) << 16);
    o.z = (u32)f2bfu_rn(b.x) | ((u32)f2bfu_rn(b.y) << 16);
    o.w = (u32)f2bfu_rn(b.z) | ((u32)f2bfu_rn(b.w) << 16);
    *(uint4*)(dst + off) = o;
}

// ---------------------------------------------------------------------------
// QKV projection GEMM, ring-3 counted-vmcnt schedule, 2 phases per K-tile.
// 128x256 tile, BK=64, 8 waves (2x4), ring-3 LDS (144KB), grid 256x3. [R15]
// ---------------------------------------------------------------------------
#define QSCALE 0.18033688011112042f   // 0.125 * log2(e)

__global__ __launch_bounds__(512) void qkv_mfma8(
    const u16* __restrict__ Xb,
    const u16* __restrict__ Wqb, const u16* __restrict__ Wkb,
    const u16* __restrict__ Wvb,
    const float* __restrict__ bq, const float* __restrict__ bk,
    const float* __restrict__ bv,
    u16* __restrict__ Qb, u16* __restrict__ Kb, u16* __restrict__ Vtb)
{
    const int which = blockIdx.y;
    const int bxl = ((blockIdx.x & 7) << 5) | (blockIdx.x >> 3);

    const u16* Asrc; const u16* Bsrc; const float* bias; u16* Out;
    int m0, n0;
    if (which == 0)      { Asrc = Xb;  Bsrc = Wqb; bias = bq; Out = Qb;
                           m0 = (bxl >> 2) * 128; n0 = (bxl & 3) * 256; }
    else if (which == 1) { Asrc = Xb;  Bsrc = Wkb; bias = bk; Out = Kb;
                           m0 = (bxl >> 2) * 128; n0 = (bxl & 3) * 256; }
    else                 { Asrc = Wvb; Bsrc = Xb;  bias = bv; Out = Vtb;
                           m0 = (bxl >> 5) * 128; n0 = (bxl & 31) * 256; }

    __shared__ u16 As[3][128][64];   // 48 KB
    __shared__ u16 Bs[3][256][64];   // 96 KB

    const int t = threadIdx.x;
    const int wave = t >> 6, lane = t & 63;
    const int qd = lane >> 4, l15 = lane & 15;
    const int wm = wave >> 2, wn = wave & 3;   // 2 x 4 wave grid

    auto STAGE_A = [&](int tt, int u) {        // u in {0,1}
        const int buf = tt % 3, k0 = tt * 64;
        const int rb = u * 64 + wave * 8;
        const int r  = rb + (lane >> 3);
        const int g  = (lane & 7) ^ (r & 7);
        gl2lds16(Asrc + (size_t)(m0 + r) * D_ + k0 + g * 8, &As[buf][rb][0]);
    };
    auto STAGE_B = [&](int tt, int q) {        // q in {0..3}
        const int buf = tt % 3, k0 = tt * 64;
        const int rb = q * 64 + wave * 8;
        const int r  = rb + (lane >> 3);
        const int g  = (lane & 7) ^ (r & 7);
        gl2lds16(Bsrc + (size_t)(n0 + r) * D_ + k0 + g * 8, &Bs[buf][rb][0]);
    };

    const f32x4 zero = {0.f, 0.f, 0.f, 0.f};
    f32x4 acc[4][4];
#pragma unroll
    for (int i = 0; i < 4; ++i)
#pragma unroll
        for (int j = 0; j < 4; ++j) acc[i][j] = zero;

#pragma unroll
    for (int u = 0; u < 2; ++u) STAGE_A(0, u);
#pragma unroll
    for (int q = 0; q < 4; ++q) STAGE_B(0, q);
#pragma unroll
    for (int u = 0; u < 2; ++u) STAGE_A(1, u);
#pragma unroll
    for (int q = 0; q < 4; ++q) STAGE_B(1, q);
    asm volatile("s_waitcnt vmcnt(6)" ::: "memory");
    __builtin_amdgcn_s_barrier();

    for (int tt = 0; tt < 16; ++tt) {
        const int buf = tt % 3;
        const bool st = tt < 14;
        const int t2 = tt + 2;

        bf16x8 bfv[4][2];
        bf16x8 af[2][2];

        // ---- phase A: read all B (8) + A mt0/mt1 (4); stage 3; 16 MFMA ----
#pragma unroll
        for (int nt = 0; nt < 4; ++nt) {
            const int row = wn * 64 + nt * 16 + l15;
#pragma unroll
            for (int ks = 0; ks < 2; ++ks)
                bfv[nt][ks] = *(const bf16x8*)&Bs[buf][row][((ks * 4 + qd) ^ (row & 7)) * 8];
        }
#pragma unroll
        for (int i = 0; i < 2; ++i) {
            const int row = wm * 64 + i * 16 + l15;
#pragma unroll
            for (int ks = 0; ks < 2; ++ks)
                af[i][ks] = *(const bf16x8*)&As[buf][row][((ks * 4 + qd) ^ (row & 7)) * 8];
        }
        if (st) { STAGE_A(t2, 0); STAGE_A(t2, 1); STAGE_B(t2, 0); }
        __builtin_amdgcn_s_barrier();
        asm volatile("s_waitcnt lgkmcnt(0)" ::: "memory");
        __builtin_amdgcn_sched_barrier(0);
        __builtin_amdgcn_s_setprio(1);
#pragma unroll
        for (int i = 0; i < 2; ++i)
#pragma unroll
            for (int ks = 0; ks < 2; ++ks)
#pragma unroll
                for (int nt = 0; nt < 4; ++nt)
                    acc[i][nt] = __builtin_amdgcn_mfma_f32_16x16x32_bf16(
                        af[i][ks], bfv[nt][ks], acc[i][nt], 0, 0, 0);
        __builtin_amdgcn_s_setprio(0);
        __builtin_amdgcn_s_barrier();

        // ---- phase B: read A mt2/mt3 (4); stage 3; 16 MFMA; vmcnt ----
#pragma unroll
        for (int i = 0; i < 2; ++i) {
            const int row = wm * 64 + (2 + i) * 16 + l15;
#pragma unroll
            for (int ks = 0; ks < 2; ++ks)
                af[i][ks] = *(const bf16x8*)&As[buf][row][((ks * 4 + qd) ^ (row & 7)) * 8];
        }
        if (st) { STAGE_B(t2, 1); STAGE_B(t2, 2); STAGE_B(t2, 3); }
        __builtin_amdgcn_s_barrier();
        asm volatile("s_waitcnt lgkmcnt(0)" ::: "memory");
        __builtin_amdgcn_sched_barrier(0);
        __builtin_amdgcn_s_setprio(1);
#pragma unroll
        for (int i = 0; i < 2; ++i)
#pragma unroll
            for (int ks = 0; ks < 2; ++ks)
#pragma unroll
                for (int nt = 0; nt < 4; ++nt)
                    acc[2 + i][nt] = __builtin_amdgcn_mfma_f32_16x16x32_bf16(
                        af[i][ks], bfv[nt][ks], acc[2 + i][nt], 0, 0, 0);
        __builtin_amdgcn_s_setprio(0);
        if (st) asm volatile("s_waitcnt vmcnt(6)" ::: "memory");
        else    asm volatile("s_waitcnt vmcnt(0)" ::: "memory");
        __builtin_amdgcn_s_barrier();
    }

    if (which < 2) {
#pragma unroll
        for (int nt = 0; nt < 4; ++nt) {
            int n = n0 + wn * 64 + nt * 16 + l15;      // feature
            float bv_ = bias[n];
            int h = n >> 6, hd = n & 63;
#pragma unroll
            for (int mt = 0; mt < 4; ++mt)
#pragma unroll
                for (int r = 0; r < 4; ++r) {
                    int m = m0 + wm * 64 + mt * 16 + qd * 4 + r;  // token
                    int bb = m >> 11, s = m & 2047;
                    float v = acc[mt][nt][r] + bv_;
                    if (which == 0) v *= QSCALE;
                    Out[(((size_t)(bb * H_ + h)) * S_ + s) * HD_ + hd] = f2bfu_rn(v);
                }
        }
    } else {
#pragma unroll
        for (int mt = 0; mt < 4; ++mt)
#pragma unroll
            for (int r = 0; r < 4; ++r) {
                int f = m0 + wm * 64 + mt * 16 + qd * 4 + r;      // feature
                float bv_ = bias[f];
                int h = f >> 6, hd = f & 63;
#pragma unroll
                for (int nt = 0; nt < 4; ++nt) {
                    int tok = n0 + wn * 64 + nt * 16 + l15;       // token
                    int bb = tok >> 11, s = tok & 2047;
                    float v = acc[mt][nt][r] + bv_;
                    Out[(((size_t)(bb * H_ + h)) * HD_ + hd) * S_ + s] = f2bfu_rn(v);
                }
            }
    }
}

// ---------------------------------------------------------------------------
// Split-K flash attention, deterministic (plain stores only).
// Grid 1-D 3072.  bid = xcd + 8*bhl + 64*rank -> bh = xcd*8 + bhl.
// rank->x remap: globally non-increasing tiles/block.  [R14]
// Swapped QK^T (S^T = mfma(K,Q)); perm-pack P pairs -> uint2 LDS stores.
// R16: mask fast path (no mb LDS); slow path loads mask per element.
// ---------------------------------------------------------------------------
__global__ __launch_bounds__(256) void attn_chunk(
    const u16* __restrict__ Qb, const u16* __restrict__ Kb,
    const u16* __restrict__ Vtb, const int* __restrict__ amask,
    float* __restrict__ Oout, float* __restrict__ Opart,
    float* __restrict__ L0, float* __restrict__ L1)
{
    const int bid = blockIdx.x;
    const int rank = bid >> 6;                      // 0..47
    int x;
    if (rank < 17)      x = rank;                   // 16-tile chunk0
    else if (rank == 17) x = 32;                    // 16-tile chunk1 (qt=31)
    else {
        int i = (rank - 18) >> 1;
        x = ((rank - 18) & 1) ? (33 + i) : (17 + i);
    }
    const int bh  = ((bid & 7) << 3) | ((bid >> 3) & 7);
    const int b = bh >> 4, h = bh & 15;
    int qt, jt0, jt1; bool second;
    if (x < 32) { qt = 31 - x; jt0 = 0;  jt1 = min(qt, 15); second = false; }
    else        { qt = 63 - x; jt0 = 16; jt1 = qt;          second = true;  }
    const int q0 = qt * 64;

    const int t = threadIdx.x;
    const int wave = t >> 6, lane = t & 63;
    const int qd = lane >> 4, l15 = lane & 15;

    __shared__ u16 Ks[64][64];     // [key][hd]  XOR-swizzled
    __shared__ u16 Vts[64][64];    // [hd][key]  XOR-swizzled
    __shared__ u16 Ps[64][72];     // [q][key]   padded (+8)

    const size_t base = (size_t)bh * S_ * HD_;
    const u16* Qg = Qb + base;
    const u16* Kg = Kb + base;
    const u16* Vg = Vtb + base;    // rows = hd, cols = s
    const int* am = amask + b * S_;

    bf16x8 qf[2];
    {
        const u16* qrow = Qg + (size_t)(q0 + wave * 16 + l15) * HD_;
        qf[0] = *(const bf16x8*)(qrow + qd * 8);
        qf[1] = *(const bf16x8*)(qrow + 32 + qd * 8);
    }
    bf16x8 onesf;
    {
        short v = (l15 == 0) ? (short)0x3F80 : (short)0;
        onesf = (bf16x8){v, v, v, v, v, v, v, v};
    }

    const f32x4 zero = {0.f, 0.f, 0.f, 0.f};
    f32x4 o[5];                    // 4 hd tiles + l tile
#pragma unroll
    for (int i = 0; i < 5; ++i) o[i] = zero;

    const int qloc = wave * 16 + l15;   // local q within the 64-row q tile
    u32* prow32 = (u32*)&Ps[qloc][0];   // this lane's P row (u32 view)

    for (int jt = jt0; jt <= jt1; ++jt) {
        const int j0 = jt * 64;
        __syncthreads();           // all waves done reading Ks/Vts
#pragma unroll
        for (int i = 0; i < 2; ++i) {
            int r0  = (wave * 2 + i) * 8;
            int row = r0 + (lane >> 3);
            int g   = (lane & 7) ^ (row & 7);
            gl2lds16(Kg + (size_t)(j0 + row) * HD_ + g * 8, &Ks[r0][0]);
            gl2lds16(Vg + (size_t)row * S_ + j0 + g * 8, &Vts[r0][0]);
        }
        // mask fast-path probe (keys j0..j0+63 covered by 4 loads x 16 l15)
        bool okl = (am[j0 + l15] != 0) & (am[j0 + 16 + l15] != 0) &
                   (am[j0 + 32 + l15] != 0) & (am[j0 + 48 + l15] != 0);
        const bool fast = __all((int)okl);
        __syncthreads();           // staging visible

        // ---- S^T = K Q^T  (swapped operands: A=K, B=Q) ----
        f32x4 sacc[4];
#pragma unroll
        for (int nt = 0; nt < 4; ++nt) sacc[nt] = zero;
        __builtin_amdgcn_s_setprio(1);
#pragma unroll
        for (int ks = 0; ks < 2; ++ks) {
#pragma unroll
            for (int nt = 0; nt < 4; ++nt) {
                int arow = nt * 16 + l15;
                int ap = (ks * 4 + qd) ^ (arow & 7);
                bf16x8 kf = *(const bf16x8*)&Ks[arow][ap * 8];
                sacc[nt] = __builtin_amdgcn_mfma_f32_16x16x32_bf16(
                    kf, qf[ks], sacc[nt], 0, 0, 0);
            }
        }
        __builtin_amdgcn_s_setprio(0);

        // ---- (mask) + causal + exp2 -> perm-pack pairs -> Ps row ----
        const bool diag = (jt == qt);
#pragma unroll
        for (int nt = 0; nt < 4; ++nt) {
            float p[4];
#pragma unroll
            for (int r = 0; r < 4; ++r) {
                int kl = nt * 16 + qd * 4 + r;       // local key
                float s = sacc[nt][r];
                if (!fast) {                         // rare: some key masked
                    if (am[j0 + kl] == 0) s = -1e30f;
                }
                if (diag && kl > qloc) s = -1e30f;
                p[r] = __builtin_amdgcn_exp2f(s);
            }
            uint2 w;
            w.x = pack_bf16(p[0], p[1]);
            w.y = pack_bf16(p[2], p[3]);
            *(uint2*)&prow32[nt * 8 + qd * 2] = w;   // keys nt*16+qd*4 .. +3
        }

        // ---- O += P V ; l += P ones (same-wave LDS rows, no barrier) ----
        __builtin_amdgcn_s_setprio(1);
#pragma unroll
        for (int ks = 0; ks < 2; ++ks) {
            int arow = wave * 16 + l15;
            bf16x8 pf = *(const bf16x8*)&Ps[arow][ks * 32 + qd * 8];
#pragma unroll
            for (int nt = 0; nt < 4; ++nt) {
                int brow = nt * 16 + l15;
                int bp = (ks * 4 + qd) ^ (brow & 7);
                bf16x8 vf = *(const bf16x8*)&Vts[brow][bp * 8];
                o[nt] = __builtin_amdgcn_mfma_f32_16x16x32_bf16(
                    pf, vf, o[nt], 0, 0, 0);
            }
            o[4] = __builtin_amdgcn_mfma_f32_16x16x32_bf16(
                pf, onesf, o[4], 0, 0, 0);
        }
        __builtin_amdgcn_s_setprio(0);
    }

    // ---- epilogue: plain stores (each destination written by ONE block) ----
    if (!second) {
        if (qt <= 15) {
#pragma unroll
            for (int r = 0; r < 4; ++r) {
                float l = __shfl(o[4][r], lane & 48);
                float inv = 1.0f / l;
                int q = q0 + wave * 16 + qd * 4 + r;
                float* op = Oout + ((size_t)(b * S_ + q)) * D_ + h * HD_;
#pragma unroll
                for (int nt = 0; nt < 4; ++nt)
                    op[nt * 16 + l15] = o[nt][r] * inv;
            }
        } else {
#pragma unroll
            for (int r = 0; r < 4; ++r) {
                int q = q0 + wave * 16 + qd * 4 + r;
                float* op = Oout + ((size_t)(b * S_ + q)) * D_ + h * HD_;
#pragma unroll
                for (int nt = 0; nt < 4; ++nt)
                    op[nt * 16 + l15] = o[nt][r];
                if (l15 == 0) L0[(size_t)bh * S_ + q] = o[4][r];
            }
        }
    } else {
#pragma unroll
        for (int r = 0; r < 4; ++r) {
            int q = q0 + wave * 16 + qd * 4 + r;
            int sh = q - 1024;
            float* op = Opart + ((size_t)bh * 1024 + sh) * HD_;
#pragma unroll
            for (int nt = 0; nt < 4; ++nt)
                op[nt * 16 + l15] = o[nt][r];
            if (l15 == 0) L1[(size_t)bh * 1024 + sh] = o[4][r];
        }
    }
}

// ---------------------------------------------------------------------------
// combine: rows s >= 1024 only.  out = (out + Opart) / (L0 + L1).
// ---------------------------------------------------------------------------
__global__ __launch_bounds__(256) void combine(
    float* __restrict__ out, const float* __restrict__ Opart,
    const float* __restrict__ L0, const float* __restrict__ L1)
{
    size_t i = ((size_t)blockIdx.x * 256 + threadIdx.x) * 4;
    int d  = (int)(i & (D_ - 1));
    int bs = (int)(i >> 10);          // b*1024 + (s-1024)
    int b  = bs >> 10, sh = bs & 1023;
    int s  = sh + 1024;
    int h  = d >> 6;
    int bh = b * H_ + h;
    float l = L0[(size_t)bh * S_ + s] + L1[(size_t)bh * 1024 + sh];
    float inv = 1.0f / l;
    float* op = out + ((size_t)(b * S_ + s)) * D_ + d;
    const float* pp = Opart + ((size_t)bh * 1024 + sh) * HD_ + (d & 63);
    float4 v = *(float4*)op;
    float4 p = *(const float4*)pp;
    v.x = (v.x + p.x) * inv; v.y = (v.y + p.y) * inv;
    v.z = (v.z + p.z) * inv; v.w = (v.w + p.w) * inv;
    *(float4*)op = v;
}

// ---------------------------------------------------------------------------
extern "C" void kernel_launch(void* const* d_in, const int* in_sizes, int n_in,
                              void* d_out, int out_size, void* d_ws, size_t ws_size,
                              hipStream_t stream) {
    (void)in_sizes; (void)n_in; (void)out_size; (void)ws_size;
    const float* X    = (const float*)d_in[0];
    const int*   mask = (const int*)d_in[1];
    const float* Wq   = (const float*)d_in[2];
    const float* bq   = (const float*)d_in[3];
    const float* Wk   = (const float*)d_in[4];
    const float* bk   = (const float*)d_in[5];
    const float* Wv   = (const float*)d_in[6];
    const float* bv   = (const float*)d_in[7];
    float* out = (float*)d_out;

    u16* Xb  = (u16*)d_ws;                 // 8192x1024 bf16
    u16* Wqb = Xb  + XN;                   // 1024x1024 bf16
    u16* Wkb = Wqb + WN;
    u16* Wvb = Wkb + WN;
    u16* Qb  = Wvb + WN;                   // [bh][s][hd]  (pre-scaled by QSCALE)
    u16* Kb  = Qb  + XN;
    u16* Vtb = Kb  + XN;                   // [bh][hd][s]
    float* Opart = (float*)(Vtb + XN);     // [bh][1024][64] fp32 (16.8 MB)
    float* L0 = Opart + (size_t)64 * 1024 * 64;   // [bh][2048]
    float* L1 = L0 + (size_t)64 * 2048;           // [bh][1024]

    convert_bf16<<<(XN + 3 * WN) / (256 * 8), 256, 0, stream>>>(
        X, Wq, Wk, Wv, Xb, Wqb, Wkb, Wvb);
    qkv_mfma8<<<dim3(256, 3), 512, 0, stream>>>(
        Xb, Wqb, Wkb, Wvb, bq, bk, bv, Qb, Kb, Vtb);
    attn_chunk<<<dim3(3072), 256, 0, stream>>>(
        Qb, Kb, Vtb, mask, out, Opart, L0, L1);
    combine<<<(B_ * 1024 * D_ / 4) / 256, 256, 0, stream>>>(out, Opart, L0, L1);
}

// Round 11
// 236.435 us; speedup vs baseline: 1.0207x; 1.0207x over previous
//
#include <hip/hip_runtime.h>
#include <hip/hip_bf16.h>
#include <math.h>

// CausalSelfAttention  B=4, S=2048, D=1024, H=16, HD=64
// R17: attn staging issue points split (same 2 barriers/tile):
//      issue K(t+1) right after post-QK^T barrier (drain covered by
//      softmax+PV); issue V(t+1) + mask-probe loads right after post-PV
//      barrier (drain covered by next QK^T; probe __all deferred to use).
//      Removes the fully-exposed ~250cy drain of the R6..R16 structure.
//      qkv (R15 2-phase ring-3), convert, combine unchanged.

#define B_ 4
#define S_ 2048
#define D_ 1024
#define H_ 16
#define HD_ 64
#define M_ (B_ * S_)   // 8192

typedef unsigned short u16;
typedef unsigned int u32;
typedef __attribute__((ext_vector_type(4))) float f32x4;
typedef __attribute__((ext_vector_type(8))) short bf16x8;   // 8 bf16 in 4 VGPRs

__device__ __forceinline__ u16 f2bfu_rn(float x) {
    u32 u = __builtin_bit_cast(u32, x);
    return (u16)((u + 0x8000u) >> 16);
}

// pack two f32 -> (bf16(hi)<<16)|bf16(lo), bit-identical to f2bfu_rn pairs.
__device__ __forceinline__ u32 pack_bf16(float lo, float hi) {
    u32 a = __builtin_bit_cast(u32, lo) + 0x8000u;
    u32 b = __builtin_bit_cast(u32, hi) + 0x8000u;
    return __builtin_amdgcn_perm(b, a, 0x07060302u);  // {b.b3,b.b2,a.b3,a.b2}
}

__device__ __forceinline__ void gl2lds16(const void* g, void* l) {
    __builtin_amdgcn_global_load_lds(
        (const __attribute__((address_space(1))) u32*)g,
        (__attribute__((address_space(3))) u32*)l, 16, 0, 0);
}

// ---------------------------------------------------------------------------
// fp32 -> bf16 conversion, 8 elems/thread
// ---------------------------------------------------------------------------
#define XN  8388608u    // 8192*1024
#define WN  1048576u    // 1024*1024
__global__ __launch_bounds__(256) void convert_bf16(
    const float* __restrict__ X,  const float* __restrict__ Wq,
    const float* __restrict__ Wk, const float* __restrict__ Wv,
    u16* __restrict__ Xb, u16* __restrict__ Wqb,
    u16* __restrict__ Wkb, u16* __restrict__ Wvb)
{
    size_t idx = ((size_t)blockIdx.x * 256 + threadIdx.x) * 8;
    const float* src; u16* dst; size_t off;
    if (idx < XN)                { src = X;  dst = Xb;  off = idx; }
    else if (idx < XN + WN)      { src = Wq; dst = Wqb; off = idx - XN; }
    else if (idx < XN + 2 * WN)  { src = Wk; dst = Wkb; off = idx - XN - WN; }
    else                         { src = Wv; dst = Wvb; off = idx - XN - 2 * WN; }
    float4 a = *(const float4*)(src + off);
    float4 b = *(const float4*)(src + off + 4);
    uint4 o;
    o.x = (u32)f2bfu_rn(a.x) | ((u32)f2bfu_rn(a.y) << 16);
    o.y = (u32)f2bfu_rn(a.z) | ((u32)f2bfu_rn(a.w) << 16);
    o.z = (u32)f2bfu_rn(b.x) | ((u32)f2bfu_rn(b.y) << 16);
    o.w = (u32)f2bfu_rn(b.z) | ((u32)f2bfu_rn(b.w) << 16);
    *(uint4*)(dst + off) = o;
}

// ---------------------------------------------------------------------------
// QKV projection GEMM, ring-3 counted-vmcnt schedule, 2 phases per K-tile.
// 128x256 tile, BK=64, 8 waves (2x4), ring-3 LDS (144KB), grid 256x3. [R15]
// ---------------------------------------------------------------------------
#define QSCALE 0.18033688011112042f   // 0.125 * log2(e)

__global__ __launch_bounds__(512) void qkv_mfma8(
    const u16* __restrict__ Xb,
    const u16* __restrict__ Wqb, const u16* __restrict__ Wkb,
    const u16* __restrict__ Wvb,
    const float* __restrict__ bq, const float* __restrict__ bk,
    const float* __restrict__ bv,
    u16* __restrict__ Qb, u16* __restrict__ Kb, u16* __restrict__ Vtb)
{
    const int which = blockIdx.y;
    const int bxl = ((blockIdx.x & 7) << 5) | (blockIdx.x >> 3);

    const u16* Asrc; const u16* Bsrc; const float* bias; u16* Out;
    int m0, n0;
    if (which == 0)      { Asrc = Xb;  Bsrc = Wqb; bias = bq; Out = Qb;
                           m0 = (bxl >> 2) * 128; n0 = (bxl & 3) * 256; }
    else if (which == 1) { Asrc = Xb;  Bsrc = Wkb; bias = bk; Out = Kb;
                           m0 = (bxl >> 2) * 128; n0 = (bxl & 3) * 256; }
    else                 { Asrc = Wvb; Bsrc = Xb;  bias = bv; Out = Vtb;
                           m0 = (bxl >> 5) * 128; n0 = (bxl & 31) * 256; }

    __shared__ u16 As[3][128][64];   // 48 KB
    __shared__ u16 Bs[3][256][64];   // 96 KB

    const int t = threadIdx.x;
    const int wave = t >> 6, lane = t & 63;
    const int qd = lane >> 4, l15 = lane & 15;
    const int wm = wave >> 2, wn = wave & 3;   // 2 x 4 wave grid

    auto STAGE_A = [&](int tt, int u) {        // u in {0,1}
        const int buf = tt % 3, k0 = tt * 64;
        const int rb = u * 64 + wave * 8;
        const int r  = rb + (lane >> 3);
        const int g  = (lane & 7) ^ (r & 7);
        gl2lds16(Asrc + (size_t)(m0 + r) * D_ + k0 + g * 8, &As[buf][rb][0]);
    };
    auto STAGE_B = [&](int tt, int q) {        // q in {0..3}
        const int buf = tt % 3, k0 = tt * 64;
        const int rb = q * 64 + wave * 8;
        const int r  = rb + (lane >> 3);
        const int g  = (lane & 7) ^ (r & 7);
        gl2lds16(Bsrc + (size_t)(n0 + r) * D_ + k0 + g * 8, &Bs[buf][rb][0]);
    };

    const f32x4 zero = {0.f, 0.f, 0.f, 0.f};
    f32x4 acc[4][4];
#pragma unroll
    for (int i = 0; i < 4; ++i)
#pragma unroll
        for (int j = 0; j < 4; ++j) acc[i][j] = zero;

#pragma unroll
    for (int u = 0; u < 2; ++u) STAGE_A(0, u);
#pragma unroll
    for (int q = 0; q < 4; ++q) STAGE_B(0, q);
#pragma unroll
    for (int u = 0; u < 2; ++u) STAGE_A(1, u);
#pragma unroll
    for (int q = 0; q < 4; ++q) STAGE_B(1, q);
    asm volatile("s_waitcnt vmcnt(6)" ::: "memory");
    __builtin_amdgcn_s_barrier();

    for (int tt = 0; tt < 16; ++tt) {
        const int buf = tt % 3;
        const bool st = tt < 14;
        const int t2 = tt + 2;

        bf16x8 bfv[4][2];
        bf16x8 af[2][2];

        // ---- phase A: read all B (8) + A mt0/mt1 (4); stage 3; 16 MFMA ----
#pragma unroll
        for (int nt = 0; nt < 4; ++nt) {
            const int row = wn * 64 + nt * 16 + l15;
#pragma unroll
            for (int ks = 0; ks < 2; ++ks)
                bfv[nt][ks] = *(const bf16x8*)&Bs[buf][row][((ks * 4 + qd) ^ (row & 7)) * 8];
        }
#pragma unroll
        for (int i = 0; i < 2; ++i) {
            const int row = wm * 64 + i * 16 + l15;
#pragma unroll
            for (int ks = 0; ks < 2; ++ks)
                af[i][ks] = *(const bf16x8*)&As[buf][row][((ks * 4 + qd) ^ (row & 7)) * 8];
        }
        if (st) { STAGE_A(t2, 0); STAGE_A(t2, 1); STAGE_B(t2, 0); }
        __builtin_amdgcn_s_barrier();
        asm volatile("s_waitcnt lgkmcnt(0)" ::: "memory");
        __builtin_amdgcn_sched_barrier(0);
        __builtin_amdgcn_s_setprio(1);
#pragma unroll
        for (int i = 0; i < 2; ++i)
#pragma unroll
            for (int ks = 0; ks < 2; ++ks)
#pragma unroll
                for (int nt = 0; nt < 4; ++nt)
                    acc[i][nt] = __builtin_amdgcn_mfma_f32_16x16x32_bf16(
                        af[i][ks], bfv[nt][ks], acc[i][nt], 0, 0, 0);
        __builtin_amdgcn_s_setprio(0);
        __builtin_amdgcn_s_barrier();

        // ---- phase B: read A mt2/mt3 (4); stage 3; 16 MFMA; vmcnt ----
#pragma unroll
        for (int i = 0; i < 2; ++i) {
            const int row = wm * 64 + (2 + i) * 16 + l15;
#pragma unroll
            for (int ks = 0; ks < 2; ++ks)
                af[i][ks] = *(const bf16x8*)&As[buf][row][((ks * 4 + qd) ^ (row & 7)) * 8];
        }
        if (st) { STAGE_B(t2, 1); STAGE_B(t2, 2); STAGE_B(t2, 3); }
        __builtin_amdgcn_s_barrier();
        asm volatile("s_waitcnt lgkmcnt(0)" ::: "memory");
        __builtin_amdgcn_sched_barrier(0);
        __builtin_amdgcn_s_setprio(1);
#pragma unroll
        for (int i = 0; i < 2; ++i)
#pragma unroll
            for (int ks = 0; ks < 2; ++ks)
#pragma unroll
                for (int nt = 0; nt < 4; ++nt)
                    acc[2 + i][nt] = __builtin_amdgcn_mfma_f32_16x16x32_bf16(
                        af[i][ks], bfv[nt][ks], acc[2 + i][nt], 0, 0, 0);
        __builtin_amdgcn_s_setprio(0);
        if (st) asm volatile("s_waitcnt vmcnt(6)" ::: "memory");
        else    asm volatile("s_waitcnt vmcnt(0)" ::: "memory");
        __builtin_amdgcn_s_barrier();
    }

    if (which < 2) {
#pragma unroll
        for (int nt = 0; nt < 4; ++nt) {
            int n = n0 + wn * 64 + nt * 16 + l15;      // feature
            float bv_ = bias[n];
            int h = n >> 6, hd = n & 63;
#pragma unroll
            for (int mt = 0; mt < 4; ++mt)
#pragma unroll
                for (int r = 0; r < 4; ++r) {
                    int m = m0 + wm * 64 + mt * 16 + qd * 4 + r;  // token
                    int bb = m >> 11, s = m & 2047;
                    float v = acc[mt][nt][r] + bv_;
                    if (which == 0) v *= QSCALE;
                    Out[(((size_t)(bb * H_ + h)) * S_ + s) * HD_ + hd] = f2bfu_rn(v);
                }
        }
    } else {
#pragma unroll
        for (int mt = 0; mt < 4; ++mt)
#pragma unroll
            for (int r = 0; r < 4; ++r) {
                int f = m0 + wm * 64 + mt * 16 + qd * 4 + r;      // feature
                float bv_ = bias[f];
                int h = f >> 6, hd = f & 63;
#pragma unroll
                for (int nt = 0; nt < 4; ++nt) {
                    int tok = n0 + wn * 64 + nt * 16 + l15;       // token
                    int bb = tok >> 11, s = tok & 2047;
                    float v = acc[mt][nt][r] + bv_;
                    Out[(((size_t)(bb * H_ + h)) * HD_ + hd) * S_ + s] = f2bfu_rn(v);
                }
            }
    }
}

// ---------------------------------------------------------------------------
// Split-K flash attention, deterministic (plain stores only).
// Grid 1-D 3072.  bid = xcd + 8*bhl + 64*rank -> bh = xcd*8 + bhl.
// rank->x remap: globally non-increasing tiles/block.  [R14]
// Swapped QK^T (S^T = mfma(K,Q)); perm-pack P pairs -> uint2 LDS stores.
// R17: split issue points — K(t+1) after post-QK^T barrier, V(t+1)+probe
//      after post-PV barrier; drains always covered by a compute phase.
// ---------------------------------------------------------------------------
__global__ __launch_bounds__(256) void attn_chunk(
    const u16* __restrict__ Qb, const u16* __restrict__ Kb,
    const u16* __restrict__ Vtb, const int* __restrict__ amask,
    float* __restrict__ Oout, float* __restrict__ Opart,
    float* __restrict__ L0, float* __restrict__ L1)
{
    const int bid = blockIdx.x;
    const int rank = bid >> 6;                      // 0..47
    int x;
    if (rank < 17)      x = rank;                   // 16-tile chunk0
    else if (rank == 17) x = 32;                    // 16-tile chunk1 (qt=31)
    else {
        int i = (rank - 18) >> 1;
        x = ((rank - 18) & 1) ? (33 + i) : (17 + i);
    }
    const int bh  = ((bid & 7) << 3) | ((bid >> 3) & 7);
    const int b = bh >> 4, h = bh & 15;
    int qt, jt0, jt1; bool second;
    if (x < 32) { qt = 31 - x; jt0 = 0;  jt1 = min(qt, 15); second = false; }
    else        { qt = 63 - x; jt0 = 16; jt1 = qt;          second = true;  }
    const int q0 = qt * 64;

    const int t = threadIdx.x;
    const int wave = t >> 6, lane = t & 63;
    const int qd = lane >> 4, l15 = lane & 15;

    __shared__ u16 Ks[64][64];     // [key][hd]  XOR-swizzled
    __shared__ u16 Vts[64][64];    // [hd][key]  XOR-swizzled
    __shared__ u16 Ps[64][72];     // [q][key]   padded (+8)

    const size_t base = (size_t)bh * S_ * HD_;
    const u16* Qg = Qb + base;
    const u16* Kg = Kb + base;
    const u16* Vg = Vtb + base;    // rows = hd, cols = s
    const int* am = amask + b * S_;

    bf16x8 qf[2];
    {
        const u16* qrow = Qg + (size_t)(q0 + wave * 16 + l15) * HD_;
        qf[0] = *(const bf16x8*)(qrow + qd * 8);
        qf[1] = *(const bf16x8*)(qrow + 32 + qd * 8);
    }
    bf16x8 onesf;
    {
        short v = (l15 == 0) ? (short)0x3F80 : (short)0;
        onesf = (bf16x8){v, v, v, v, v, v, v, v};
    }

    const f32x4 zero = {0.f, 0.f, 0.f, 0.f};
    f32x4 o[5];                    // 4 hd tiles + l tile
#pragma unroll
    for (int i = 0; i < 5; ++i) o[i] = zero;

    const int qloc = wave * 16 + l15;   // local q within the 64-row q tile
    u32* prow32 = (u32*)&Ps[qloc][0];   // this lane's P row (u32 view)

    // staging helpers (pre-swizzled source addresses, linear LDS rows)
    auto ISSUE_K = [&](int jt) {
        const int j0 = jt * 64;
#pragma unroll
        for (int i = 0; i < 2; ++i) {
            int r0  = (wave * 2 + i) * 8;
            int row = r0 + (lane >> 3);
            int g   = (lane & 7) ^ (row & 7);
            gl2lds16(Kg + (size_t)(j0 + row) * HD_ + g * 8, &Ks[r0][0]);
        }
    };
    auto ISSUE_V = [&](int jt) {
        const int j0 = jt * 64;
#pragma unroll
        for (int i = 0; i < 2; ++i) {
            int r0  = (wave * 2 + i) * 8;
            int row = r0 + (lane >> 3);
            int g   = (lane & 7) ^ (row & 7);
            gl2lds16(Vg + (size_t)row * S_ + j0 + g * 8, &Vts[r0][0]);
        }
    };

    // mask probe words for the CURRENT tile (loads issued one phase early;
    // __all deferred to point of use so the load latency hides)
    int am0, am1, am2, am3;
    auto PROBE = [&](int jt) {
        const int j0 = jt * 64;
        am0 = am[j0 + l15];      am1 = am[j0 + 16 + l15];
        am2 = am[j0 + 32 + l15]; am3 = am[j0 + 48 + l15];
    };

    // ---- prologue: stage tile jt0 ----
    ISSUE_K(jt0);
    ISSUE_V(jt0);
    PROBE(jt0);
    __syncthreads();               // drain K+V(jt0); all waves ready

    for (int jt = jt0; jt <= jt1; ++jt) {
        const int j0 = jt * 64;

        // ---- S^T = K Q^T  (swapped operands: A=K, B=Q) ----
        f32x4 sacc[4];
#pragma unroll
        for (int nt = 0; nt < 4; ++nt) sacc[nt] = zero;
        __builtin_amdgcn_s_setprio(1);
#pragma unroll
        for (int ks = 0; ks < 2; ++ks) {
#pragma unroll
            for (int nt = 0; nt < 4; ++nt) {
                int arow = nt * 16 + l15;
                int ap = (ks * 4 + qd) ^ (arow & 7);
                bf16x8 kf = *(const bf16x8*)&Ks[arow][ap * 8];
                sacc[nt] = __builtin_amdgcn_mfma_f32_16x16x32_bf16(
                    kf, qf[ks], sacc[nt], 0, 0, 0);
            }
        }
        __builtin_amdgcn_s_setprio(0);

        __syncthreads();           // (A) Ks readers done; drains V(jt)
        if (jt < jt1) ISSUE_K(jt + 1);   // flies under softmax+PV

        // ---- (mask) + causal + exp2 -> perm-pack pairs -> Ps row ----
        const bool fast = __all((int)((am0 != 0) & (am1 != 0) &
                                      (am2 != 0) & (am3 != 0)));
        const bool diag = (jt == qt);
#pragma unroll
        for (int nt = 0; nt < 4; ++nt) {
            float p[4];
#pragma unroll
            for (int r = 0; r < 4; ++r) {
                int kl = nt * 16 + qd * 4 + r;       // local key
                float s = sacc[nt][r];
                if (!fast) {                         // rare: some key masked
                    if (am[j0 + kl] == 0) s = -1e30f;
                }
                if (diag && kl > qloc) s = -1e30f;
                p[r] = __builtin_amdgcn_exp2f(s);
            }
            uint2 w;
            w.x = pack_bf16(p[0], p[1]);
            w.y = pack_bf16(p[2], p[3]);
            *(uint2*)&prow32[nt * 8 + qd * 2] = w;   // keys nt*16+qd*4 .. +3
        }

        // ---- O += P V ; l += P ones (same-wave LDS rows, no barrier) ----
        __builtin_amdgcn_s_setprio(1);
#pragma unroll
        for (int ks = 0; ks < 2; ++ks) {
            int arow = wave * 16 + l15;
            bf16x8 pf = *(const bf16x8*)&Ps[arow][ks * 32 + qd * 8];
#pragma unroll
            for (int nt = 0; nt < 4; ++nt) {
                int brow = nt * 16 + l15;
                int bp = (ks * 4 + qd) ^ (brow & 7);
                bf16x8 vf = *(const bf16x8*)&Vts[brow][bp * 8];
                o[nt] = __builtin_amdgcn_mfma_f32_16x16x32_bf16(
                    pf, vf, o[nt], 0, 0, 0);
            }
            o[4] = __builtin_amdgcn_mfma_f32_16x16x32_bf16(
                pf, onesf, o[4], 0, 0, 0);
        }
        __builtin_amdgcn_s_setprio(0);

        if (jt < jt1) {
            __syncthreads();       // (B) Vts readers done; drains K(jt+1)
            ISSUE_V(jt + 1);       // flies under next QK^T
            PROBE(jt + 1);         // loads issued; __all deferred
        }
    }

    // ---- epilogue: plain stores (each destination written by ONE block) ----
    if (!second) {
        if (qt <= 15) {
#pragma unroll
            for (int r = 0; r < 4; ++r) {
                float l = __shfl(o[4][r], lane & 48);
                float inv = 1.0f / l;
                int q = q0 + wave * 16 + qd * 4 + r;
                float* op = Oout + ((size_t)(b * S_ + q)) * D_ + h * HD_;
#pragma unroll
                for (int nt = 0; nt < 4; ++nt)
                    op[nt * 16 + l15] = o[nt][r] * inv;
            }
        } else {
#pragma unroll
            for (int r = 0; r < 4; ++r) {
                int q = q0 + wave * 16 + qd * 4 + r;
                float* op = Oout + ((size_t)(b * S_ + q)) * D_ + h * HD_;
#pragma unroll
                for (int nt = 0; nt < 4; ++nt)
                    op[nt * 16 + l15] = o[nt][r];
                if (l15 == 0) L0[(size_t)bh * S_ + q] = o[4][r];
            }
        }
    } else {
#pragma unroll
        for (int r = 0; r < 4; ++r) {
            int q = q0 + wave * 16 + qd * 4 + r;
            int sh = q - 1024;
            float* op = Opart + ((size_t)bh * 1024 + sh) * HD_;
#pragma unroll
            for (int nt = 0; nt < 4; ++nt)
                op[nt * 16 + l15] = o[nt][r];
            if (l15 == 0) L1[(size_t)bh * 1024 + sh] = o[4][r];
        }
    }
}

// ---------------------------------------------------------------------------
// combine: rows s >= 1024 only.  out = (out + Opart) / (L0 + L1).
// ---------------------------------------------------------------------------
__global__ __launch_bounds__(256) void combine(
    float* __restrict__ out, const float* __restrict__ Opart,
    const float* __restrict__ L0, const float* __restrict__ L1)
{
    size_t i = ((size_t)blockIdx.x * 256 + threadIdx.x) * 4;
    int d  = (int)(i & (D_ - 1));
    int bs = (int)(i >> 10);          // b*1024 + (s-1024)
    int b  = bs >> 10, sh = bs & 1023;
    int s  = sh + 1024;
    int h  = d >> 6;
    int bh = b * H_ + h;
    float l = L0[(size_t)bh * S_ + s] + L1[(size_t)bh * 1024 + sh];
    float inv = 1.0f / l;
    float* op = out + ((size_t)(b * S_ + s)) * D_ + d;
    const float* pp = Opart + ((size_t)bh * 1024 + sh) * HD_ + (d & 63);
    float4 v = *(float4*)op;
    float4 p = *(const float4*)pp;
    v.x = (v.x + p.x) * inv; v.y = (v.y + p.y) * inv;
    v.z = (v.z + p.z) * inv; v.w = (v.w + p.w) * inv;
    *(float4*)op = v;
}

// ---------------------------------------------------------------------------
extern "C" void kernel_launch(void* const* d_in, const int* in_sizes, int n_in,
                              void* d_out, int out_size, void* d_ws, size_t ws_size,
                              hipStream_t stream) {
    (void)in_sizes; (void)n_in; (void)out_size; (void)ws_size;
    const float* X    = (const float*)d_in[0];
    const int*   mask = (const int*)d_in[1];
    const float* Wq   = (const float*)d_in[2];
    const float* bq   = (const float*)d_in[3];
    const float* Wk   = (const float*)d_in[4];
    const float* bk   = (const float*)d_in[5];
    const float* Wv   = (const float*)d_in[6];
    const float* bv   = (const float*)d_in[7];
    float* out = (float*)d_out;

    u16* Xb  = (u16*)d_ws;                 // 8192x1024 bf16
    u16* Wqb = Xb  + XN;                   // 1024x1024 bf16
    u16* Wkb = Wqb + WN;
    u16* Wvb = Wkb + WN;
    u16* Qb  = Wvb + WN;                   // [bh][s][hd]  (pre-scaled by QSCALE)
    u16* Kb  = Qb  + XN;
    u16* Vtb = Kb  + XN;                   // [bh][hd][s]
    float* Opart = (float*)(Vtb + XN);     // [bh][1024][64] fp32 (16.8 MB)
    float* L0 = Opart + (size_t)64 * 1024 * 64;   // [bh][2048]
    float* L1 = L0 + (size_t)64 * 2048;           // [bh][1024]

    convert_bf16<<<(XN + 3 * WN) / (256 * 8), 256, 0, stream>>>(
        X, Wq, Wk, Wv, Xb, Wqb, Wkb, Wvb);
    qkv_mfma8<<<dim3(256, 3), 512, 0, stream>>>(
        Xb, Wqb, Wkb, Wvb, bq, bk, bv, Qb, Kb, Vtb);
    attn_chunk<<<dim3(3072), 256, 0, stream>>>(
        Qb, Kb, Vtb, mask, out, Opart, L0, L1);
    combine<<<(B_ * 1024 * D_ / 4) / 256, 256, 0, stream>>>(out, Opart, L0, L1);
}

// Round 12
// 232.039 us; speedup vs baseline: 1.0400x; 1.0189x over previous
//
#include <hip/hip_runtime.h>
#include <hip/hip_bf16.h>
#include <math.h>

// CausalSelfAttention  B=4, S=2048, D=1024, H=16, HD=64
// R18: qkv rebuilt at BK=32, ring-3 = 72KB LDS -> 2 blocks/CU (16 waves/CU,
//      2x residency) and ONE barrier per K-tile (32 total vs R15's 64):
//      per tile {8 ds_read, 3 gl2lds (t+2), lgkm0, 16 MFMA, vmcnt(3), bar}.
//      64B-row swizzle: chunk p = qd ^ ((row>>1)&3) -> 2-way (free);
//      gl2lds source pre-swizzled with the same involution.
//      attn (R17), convert, combine unchanged.

#define B_ 4
#define S_ 2048
#define D_ 1024
#define H_ 16
#define HD_ 64
#define M_ (B_ * S_)   // 8192

typedef unsigned short u16;
typedef unsigned int u32;
typedef __attribute__((ext_vector_type(4))) float f32x4;
typedef __attribute__((ext_vector_type(8))) short bf16x8;   // 8 bf16 in 4 VGPRs

__device__ __forceinline__ u16 f2bfu_rn(float x) {
    u32 u = __builtin_bit_cast(u32, x);
    return (u16)((u + 0x8000u) >> 16);
}

// pack two f32 -> (bf16(hi)<<16)|bf16(lo), bit-identical to f2bfu_rn pairs.
__device__ __forceinline__ u32 pack_bf16(float lo, float hi) {
    u32 a = __builtin_bit_cast(u32, lo) + 0x8000u;
    u32 b = __builtin_bit_cast(u32, hi) + 0x8000u;
    return __builtin_amdgcn_perm(b, a, 0x07060302u);  // {b.b3,b.b2,a.b3,a.b2}
}

__device__ __forceinline__ void gl2lds16(const void* g, void* l) {
    __builtin_amdgcn_global_load_lds(
        (const __attribute__((address_space(1))) u32*)g,
        (__attribute__((address_space(3))) u32*)l, 16, 0, 0);
}

// ---------------------------------------------------------------------------
// fp32 -> bf16 conversion, 8 elems/thread
// ---------------------------------------------------------------------------
#define XN  8388608u    // 8192*1024
#define WN  1048576u    // 1024*1024
__global__ __launch_bounds__(256) void convert_bf16(
    const float* __restrict__ X,  const float* __restrict__ Wq,
    const float* __restrict__ Wk, const float* __restrict__ Wv,
    u16* __restrict__ Xb, u16* __restrict__ Wqb,
    u16* __restrict__ Wkb, u16* __restrict__ Wvb)
{
    size_t idx = ((size_t)blockIdx.x * 256 + threadIdx.x) * 8;
    const float* src; u16* dst; size_t off;
    if (idx < XN)                { src = X;  dst = Xb;  off = idx; }
    else if (idx < XN + WN)      { src = Wq; dst = Wqb; off = idx - XN; }
    else if (idx < XN + 2 * WN)  { src = Wk; dst = Wkb; off = idx - XN - WN; }
    else                         { src = Wv; dst = Wvb; off = idx - XN - 2 * WN; }
    float4 a = *(const float4*)(src + off);
    float4 b = *(const float4*)(src + off + 4);
    uint4 o;
    o.x = (u32)f2bfu_rn(a.x) | ((u32)f2bfu_rn(a.y) << 16);
    o.y = (u32)f2bfu_rn(a.z) | ((u32)f2bfu_rn(a.w) << 16);
    o.z = (u32)f2bfu_rn(b.x) | ((u32)f2bfu_rn(b.y) << 16);
    o.w = (u32)f2bfu_rn(b.z) | ((u32)f2bfu_rn(b.w) << 16);
    *(uint4*)(dst + off) = o;
}

// ---------------------------------------------------------------------------
// QKV projection GEMM: 128x256 tile, BK=32, ring-3 LDS (72KB), 8 waves (2x4),
// 1 barrier per K-tile, counted vmcnt(3).  Grid 256x3 (XCD-chunk swizzled).
// z=0: A=X, B=Wq -> Q = (X Wq^T + bq)*QSCALE -> [bh][s][hd]
// z=1: A=X, B=Wk -> K -> [bh][s][hd]
// z=2: A=Wv, B=X -> V^T -> [bh][hd][s]
// ---------------------------------------------------------------------------
#define QSCALE 0.18033688011112042f   // 0.125 * log2(e)

__global__ __launch_bounds__(512) void qkv_mfma8(
    const u16* __restrict__ Xb,
    const u16* __restrict__ Wqb, const u16* __restrict__ Wkb,
    const u16* __restrict__ Wvb,
    const float* __restrict__ bq, const float* __restrict__ bk,
    const float* __restrict__ bv,
    u16* __restrict__ Qb, u16* __restrict__ Kb, u16* __restrict__ Vtb)
{
    const int which = blockIdx.y;
    const int bxl = ((blockIdx.x & 7) << 5) | (blockIdx.x >> 3);

    const u16* Asrc; const u16* Bsrc; const float* bias; u16* Out;
    int m0, n0;
    if (which == 0)      { Asrc = Xb;  Bsrc = Wqb; bias = bq; Out = Qb;
                           m0 = (bxl >> 2) * 128; n0 = (bxl & 3) * 256; }
    else if (which == 1) { Asrc = Xb;  Bsrc = Wkb; bias = bk; Out = Kb;
                           m0 = (bxl >> 2) * 128; n0 = (bxl & 3) * 256; }
    else                 { Asrc = Wvb; Bsrc = Xb;  bias = bv; Out = Vtb;
                           m0 = (bxl >> 5) * 128; n0 = (bxl & 31) * 256; }

    __shared__ u16 As[3][128][32];   // 24 KB
    __shared__ u16 Bs[3][256][32];   // 48 KB

    const int t = threadIdx.x;
    const int wave = t >> 6, lane = t & 63;
    const int qd = lane >> 4, l15 = lane & 15;
    const int wm = wave >> 2, wn = wave & 3;   // 2 x 4 wave grid

    // stage K-tile tt (32-wide): A = 1 gl2lds/wave (16 rows), B = 2/wave.
    // LDS rows are linear; source chunk pre-swizzled: g = (lane&3)^((r>>1)&3).
    auto STAGE_A = [&](int tt) {
        const int buf = tt % 3, k0 = tt * 32;
        const int rb = wave * 16;
        const int r  = rb + (lane >> 2);
        const int g  = (lane & 3) ^ ((r >> 1) & 3);
        gl2lds16(Asrc + (size_t)(m0 + r) * D_ + k0 + g * 8, &As[buf][rb][0]);
    };
    auto STAGE_B = [&](int tt, int u) {        // u in {0,1}
        const int buf = tt % 3, k0 = tt * 32;
        const int rb = (wave * 2 + u) * 16;
        const int r  = rb + (lane >> 2);
        const int g  = (lane & 3) ^ ((r >> 1) & 3);
        gl2lds16(Bsrc + (size_t)(n0 + r) * D_ + k0 + g * 8, &Bs[buf][rb][0]);
    };

    const f32x4 zero = {0.f, 0.f, 0.f, 0.f};
    f32x4 acc[4][4];
#pragma unroll
    for (int i = 0; i < 4; ++i)
#pragma unroll
        for (int j = 0; j < 4; ++j) acc[i][j] = zero;

    // ---- prologue: stage tiles 0 and 1; make tile 0 resident ----
    STAGE_A(0); STAGE_B(0, 0); STAGE_B(0, 1);
    STAGE_A(1); STAGE_B(1, 0); STAGE_B(1, 1);
    asm volatile("s_waitcnt vmcnt(3)" ::: "memory");
    __builtin_amdgcn_s_barrier();

    for (int tt = 0; tt < 32; ++tt) {
        const int buf = tt % 3;

        bf16x8 af[4], bfv[4];
#pragma unroll
        for (int nt = 0; nt < 4; ++nt) {
            const int row = wn * 64 + nt * 16 + l15;
            bfv[nt] = *(const bf16x8*)&Bs[buf][row][(qd ^ ((row >> 1) & 3)) * 8];
        }
#pragma unroll
        for (int mt = 0; mt < 4; ++mt) {
            const int row = wm * 64 + mt * 16 + l15;
            af[mt] = *(const bf16x8*)&As[buf][row][(qd ^ ((row >> 1) & 3)) * 8];
        }
        if (tt <= 29) {                 // stage tile tt+2 into (tt+2)%3
            const int t2 = tt + 2;      // overwrites (tt-1)%3: readers done
            STAGE_A(t2); STAGE_B(t2, 0); STAGE_B(t2, 1);
        }
        asm volatile("s_waitcnt lgkmcnt(0)" ::: "memory");
        __builtin_amdgcn_sched_barrier(0);
        __builtin_amdgcn_s_setprio(1);
#pragma unroll
        for (int mt = 0; mt < 4; ++mt)
#pragma unroll
            for (int nt = 0; nt < 4; ++nt)
                acc[mt][nt] = __builtin_amdgcn_mfma_f32_16x16x32_bf16(
                    af[mt], bfv[nt], acc[mt][nt], 0, 0, 0);
        __builtin_amdgcn_s_setprio(0);
        // boundary: retire tile tt+1's 3 issues (FIFO), keep tt+2's in flight
        if (tt <= 28) asm volatile("s_waitcnt vmcnt(3)" ::: "memory");
        else          asm volatile("s_waitcnt vmcnt(0)" ::: "memory");
        __builtin_amdgcn_s_barrier();
    }

    // ---- epilogue: C/D layout row = qd*4 + reg, col = l15 ----
    if (which < 2) {
#pragma unroll
        for (int nt = 0; nt < 4; ++nt) {
            int n = n0 + wn * 64 + nt * 16 + l15;      // feature
            float bv_ = bias[n];
            int h = n >> 6, hd = n & 63;
#pragma unroll
            for (int mt = 0; mt < 4; ++mt)
#pragma unroll
                for (int r = 0; r < 4; ++r) {
                    int m = m0 + wm * 64 + mt * 16 + qd * 4 + r;  // token
                    int bb = m >> 11, s = m & 2047;
                    float v = acc[mt][nt][r] + bv_;
                    if (which == 0) v *= QSCALE;
                    Out[(((size_t)(bb * H_ + h)) * S_ + s) * HD_ + hd] = f2bfu_rn(v);
                }
        }
    } else {
#pragma unroll
        for (int mt = 0; mt < 4; ++mt)
#pragma unroll
            for (int r = 0; r < 4; ++r) {
                int f = m0 + wm * 64 + mt * 16 + qd * 4 + r;      // feature
                float bv_ = bias[f];
                int h = f >> 6, hd = f & 63;
#pragma unroll
                for (int nt = 0; nt < 4; ++nt) {
                    int tok = n0 + wn * 64 + nt * 16 + l15;       // token
                    int bb = tok >> 11, s = tok & 2047;
                    float v = acc[mt][nt][r] + bv_;
                    Out[(((size_t)(bb * H_ + h)) * HD_ + hd) * S_ + s] = f2bfu_rn(v);
                }
            }
    }
}

// ---------------------------------------------------------------------------
// Split-K flash attention, deterministic (plain stores only).  [R17, kept]
// Grid 1-D 3072.  bid = xcd + 8*bhl + 64*rank -> bh = xcd*8 + bhl.
// rank->x remap: globally non-increasing tiles/block.
// Swapped QK^T (S^T = mfma(K,Q)); perm-pack P pairs -> uint2 LDS stores.
// Split issue points: K(t+1) after post-QK^T barrier, V(t+1)+probe after
// post-PV barrier; drains always covered by a compute phase.
// ---------------------------------------------------------------------------
__global__ __launch_bounds__(256) void attn_chunk(
    const u16* __restrict__ Qb, const u16* __restrict__ Kb,
    const u16* __restrict__ Vtb, const int* __restrict__ amask,
    float* __restrict__ Oout, float* __restrict__ Opart,
    float* __restrict__ L0, float* __restrict__ L1)
{
    const int bid = blockIdx.x;
    const int rank = bid >> 6;                      // 0..47
    int x;
    if (rank < 17)      x = rank;                   // 16-tile chunk0
    else if (rank == 17) x = 32;                    // 16-tile chunk1 (qt=31)
    else {
        int i = (rank - 18) >> 1;
        x = ((rank - 18) & 1) ? (33 + i) : (17 + i);
    }
    const int bh  = ((bid & 7) << 3) | ((bid >> 3) & 7);
    const int b = bh >> 4, h = bh & 15;
    int qt, jt0, jt1; bool second;
    if (x < 32) { qt = 31 - x; jt0 = 0;  jt1 = min(qt, 15); second = false; }
    else        { qt = 63 - x; jt0 = 16; jt1 = qt;          second = true;  }
    const int q0 = qt * 64;

    const int t = threadIdx.x;
    const int wave = t >> 6, lane = t & 63;
    const int qd = lane >> 4, l15 = lane & 15;

    __shared__ u16 Ks[64][64];     // [key][hd]  XOR-swizzled
    __shared__ u16 Vts[64][64];    // [hd][key]  XOR-swizzled
    __shared__ u16 Ps[64][72];     // [q][key]   padded (+8)

    const size_t base = (size_t)bh * S_ * HD_;
    const u16* Qg = Qb + base;
    const u16* Kg = Kb + base;
    const u16* Vg = Vtb + base;    // rows = hd, cols = s
    const int* am = amask + b * S_;

    bf16x8 qf[2];
    {
        const u16* qrow = Qg + (size_t)(q0 + wave * 16 + l15) * HD_;
        qf[0] = *(const bf16x8*)(qrow + qd * 8);
        qf[1] = *(const bf16x8*)(qrow + 32 + qd * 8);
    }
    bf16x8 onesf;
    {
        short v = (l15 == 0) ? (short)0x3F80 : (short)0;
        onesf = (bf16x8){v, v, v, v, v, v, v, v};
    }

    const f32x4 zero = {0.f, 0.f, 0.f, 0.f};
    f32x4 o[5];                    // 4 hd tiles + l tile
#pragma unroll
    for (int i = 0; i < 5; ++i) o[i] = zero;

    const int qloc = wave * 16 + l15;   // local q within the 64-row q tile
    u32* prow32 = (u32*)&Ps[qloc][0];   // this lane's P row (u32 view)

    // staging helpers (pre-swizzled source addresses, linear LDS rows)
    auto ISSUE_K = [&](int jt) {
        const int j0 = jt * 64;
#pragma unroll
        for (int i = 0; i < 2; ++i) {
            int r0  = (wave * 2 + i) * 8;
            int row = r0 + (lane >> 3);
            int g   = (lane & 7) ^ (row & 7);
            gl2lds16(Kg + (size_t)(j0 + row) * HD_ + g * 8, &Ks[r0][0]);
        }
    };
    auto ISSUE_V = [&](int jt) {
        const int j0 = jt * 64;
#pragma unroll
        for (int i = 0; i < 2; ++i) {
            int r0  = (wave * 2 + i) * 8;
            int row = r0 + (lane >> 3);
            int g   = (lane & 7) ^ (row & 7);
            gl2lds16(Vg + (size_t)row * S_ + j0 + g * 8, &Vts[r0][0]);
        }
    };

    // mask probe words for the CURRENT tile (loads issued one phase early;
    // __all deferred to point of use so the load latency hides)
    int am0, am1, am2, am3;
    auto PROBE = [&](int jt) {
        const int j0 = jt * 64;
        am0 = am[j0 + l15];      am1 = am[j0 + 16 + l15];
        am2 = am[j0 + 32 + l15]; am3 = am[j0 + 48 + l15];
    };

    // ---- prologue: stage tile jt0 ----
    ISSUE_K(jt0);
    ISSUE_V(jt0);
    PROBE(jt0);
    __syncthreads();               // drain K+V(jt0); all waves ready

    for (int jt = jt0; jt <= jt1; ++jt) {
        const int j0 = jt * 64;

        // ---- S^T = K Q^T  (swapped operands: A=K, B=Q) ----
        f32x4 sacc[4];
#pragma unroll
        for (int nt = 0; nt < 4; ++nt) sacc[nt] = zero;
        __builtin_amdgcn_s_setprio(1);
#pragma unroll
        for (int ks = 0; ks < 2; ++ks) {
#pragma unroll
            for (int nt = 0; nt < 4; ++nt) {
                int arow = nt * 16 + l15;
                int ap = (ks * 4 + qd) ^ (arow & 7);
                bf16x8 kf = *(const bf16x8*)&Ks[arow][ap * 8];
                sacc[nt] = __builtin_amdgcn_mfma_f32_16x16x32_bf16(
                    kf, qf[ks], sacc[nt], 0, 0, 0);
            }
        }
        __builtin_amdgcn_s_setprio(0);

        __syncthreads();           // (A) Ks readers done; drains V(jt)
        if (jt < jt1) ISSUE_K(jt + 1);   // flies under softmax+PV

        // ---- (mask) + causal + exp2 -> perm-pack pairs -> Ps row ----
        const bool fast = __all((int)((am0 != 0) & (am1 != 0) &
                                      (am2 != 0) & (am3 != 0)));
        const bool diag = (jt == qt);
#pragma unroll
        for (int nt = 0; nt < 4; ++nt) {
            float p[4];
#pragma unroll
            for (int r = 0; r < 4; ++r) {
                int kl = nt * 16 + qd * 4 + r;       // local key
                float s = sacc[nt][r];
                if (!fast) {                         // rare: some key masked
                    if (am[j0 + kl] == 0) s = -1e30f;
                }
                if (diag && kl > qloc) s = -1e30f;
                p[r] = __builtin_amdgcn_exp2f(s);
            }
            uint2 w;
            w.x = pack_bf16(p[0], p[1]);
            w.y = pack_bf16(p[2], p[3]);
            *(uint2*)&prow32[nt * 8 + qd * 2] = w;   // keys nt*16+qd*4 .. +3
        }

        // ---- O += P V ; l += P ones (same-wave LDS rows, no barrier) ----
        __builtin_amdgcn_s_setprio(1);
#pragma unroll
        for (int ks = 0; ks < 2; ++ks) {
            int arow = wave * 16 + l15;
            bf16x8 pf = *(const bf16x8*)&Ps[arow][ks * 32 + qd * 8];
#pragma unroll
            for (int nt = 0; nt < 4; ++nt) {
                int brow = nt * 16 + l15;
                int bp = (ks * 4 + qd) ^ (brow & 7);
                bf16x8 vf = *(const bf16x8*)&Vts[brow][bp * 8];
                o[nt] = __builtin_amdgcn_mfma_f32_16x16x32_bf16(
                    pf, vf, o[nt], 0, 0, 0);
            }
            o[4] = __builtin_amdgcn_mfma_f32_16x16x32_bf16(
                pf, onesf, o[4], 0, 0, 0);
        }
        __builtin_amdgcn_s_setprio(0);

        if (jt < jt1) {
            __syncthreads();       // (B) Vts readers done; drains K(jt+1)
            ISSUE_V(jt + 1);       // flies under next QK^T
            PROBE(jt + 1);         // loads issued; __all deferred
        }
    }

    // ---- epilogue: plain stores (each destination written by ONE block) ----
    if (!second) {
        if (qt <= 15) {
#pragma unroll
            for (int r = 0; r < 4; ++r) {
                float l = __shfl(o[4][r], lane & 48);
                float inv = 1.0f / l;
                int q = q0 + wave * 16 + qd * 4 + r;
                float* op = Oout + ((size_t)(b * S_ + q)) * D_ + h * HD_;
#pragma unroll
                for (int nt = 0; nt < 4; ++nt)
                    op[nt * 16 + l15] = o[nt][r] * inv;
            }
        } else {
#pragma unroll
            for (int r = 0; r < 4; ++r) {
                int q = q0 + wave * 16 + qd * 4 + r;
                float* op = Oout + ((size_t)(b * S_ + q)) * D_ + h * HD_;
#pragma unroll
                for (int nt = 0; nt < 4; ++nt)
                    op[nt * 16 + l15] = o[nt][r];
                if (l15 == 0) L0[(size_t)bh * S_ + q] = o[4][r];
            }
        }
    } else {
#pragma unroll
        for (int r = 0; r < 4; ++r) {
            int q = q0 + wave * 16 + qd * 4 + r;
            int sh = q - 1024;
            float* op = Opart + ((size_t)bh * 1024 + sh) * HD_;
#pragma unroll
            for (int nt = 0; nt < 4; ++nt)
                op[nt * 16 + l15] = o[nt][r];
            if (l15 == 0) L1[(size_t)bh * 1024 + sh] = o[4][r];
        }
    }
}

// ---------------------------------------------------------------------------
// combine: rows s >= 1024 only.  out = (out + Opart) / (L0 + L1).
// ---------------------------------------------------------------------------
__global__ __launch_bounds__(256) void combine(
    float* __restrict__ out, const float* __restrict__ Opart,
    const float* __restrict__ L0, const float* __restrict__ L1)
{
    size_t i = ((size_t)blockIdx.x * 256 + threadIdx.x) * 4;
    int d  = (int)(i & (D_ - 1));
    int bs = (int)(i >> 10);          // b*1024 + (s-1024)
    int b  = bs >> 10, sh = bs & 1023;
    int s  = sh + 1024;
    int h  = d >> 6;
    int bh = b * H_ + h;
    float l = L0[(size_t)bh * S_ + s] + L1[(size_t)bh * 1024 + sh];
    float inv = 1.0f / l;
    float* op = out + ((size_t)(b * S_ + s)) * D_ + d;
    const float* pp = Opart + ((size_t)bh * 1024 + sh) * HD_ + (d & 63);
    float4 v = *(float4*)op;
    float4 p = *(const float4*)pp;
    v.x = (v.x + p.x) * inv; v.y = (v.y + p.y) * inv;
    v.z = (v.z + p.z) * inv; v.w = (v.w + p.w) * inv;
    *(float4*)op = v;
}

// ---------------------------------------------------------------------------
extern "C" void kernel_launch(void* const* d_in, const int* in_sizes, int n_in,
                              void* d_out, int out_size, void* d_ws, size_t ws_size,
                              hipStream_t stream) {
    (void)in_sizes; (void)n_in; (void)out_size; (void)ws_size;
    const float* X    = (const float*)d_in[0];
    const int*   mask = (const int*)d_in[1];
    const float* Wq   = (const float*)d_in[2];
    const float* bq   = (const float*)d_in[3];
    const float* Wk   = (const float*)d_in[4];
    const float* bk   = (const float*)d_in[5];
    const float* Wv   = (const float*)d_in[6];
    const float* bv   = (const float*)d_in[7];
    float* out = (float*)d_out;

    u16* Xb  = (u16*)d_ws;                 // 8192x1024 bf16
    u16* Wqb = Xb  + XN;                   // 1024x1024 bf16
    u16* Wkb = Wqb + WN;
    u16* Wvb = Wkb + WN;
    u16* Qb  = Wvb + WN;                   // [bh][s][hd]  (pre-scaled by QSCALE)
    u16* Kb  = Qb  + XN;
    u16* Vtb = Kb  + XN;                   // [bh][hd][s]
    float* Opart = (float*)(Vtb + XN);     // [bh][1024][64] fp32 (16.8 MB)
    float* L0 = Opart + (size_t)64 * 1024 * 64;   // [bh][2048]
    float* L1 = L0 + (size_t)64 * 2048;           // [bh][1024]

    convert_bf16<<<(XN + 3 * WN) / (256 * 8), 256, 0, stream>>>(
        X, Wq, Wk, Wv, Xb, Wqb, Wkb, Wvb);
    qkv_mfma8<<<dim3(256, 3), 512, 0, stream>>>(
        Xb, Wqb, Wkb, Wvb, bq, bk, bv, Qb, Kb, Vtb);
    attn_chunk<<<dim3(3072), 256, 0, stream>>>(
        Qb, Kb, Vtb, mask, out, Opart, L0, L1);
    combine<<<(B_ * 1024 * D_ / 4) / 256, 256, 0, stream>>>(out, Opart, L0, L1);
}

// Round 13
// 231.150 us; speedup vs baseline: 1.0440x; 1.0038x over previous
//
#include <hip/hip_runtime.h>
#include <hip/hip_bf16.h>
#include <math.h>

// CausalSelfAttention  B=4, S=2048, D=1024, H=16, HD=64
// R19: qkv at 128x128 tile, 4 waves (2x2), BK=32, ring-3 = 48KB LDS
//      -> 3 blocks/CU (12 waves, 3 independent barrier groups), grid
//      512x3 = 1536 blocks = EXACTLY 2 dispatch rounds of 768 slots.
//      Per-wave inner loop identical to R18 (64x64 wave-tile, 8 ds_read :
//      16 MFMA, 1 barrier/K-tile, counted vmcnt(4), same 2-way swizzle).
//      attn (R17), convert, combine unchanged.

#define B_ 4
#define S_ 2048
#define D_ 1024
#define H_ 16
#define HD_ 64
#define M_ (B_ * S_)   // 8192

typedef unsigned short u16;
typedef unsigned int u32;
typedef __attribute__((ext_vector_type(4))) float f32x4;
typedef __attribute__((ext_vector_type(8))) short bf16x8;   // 8 bf16 in 4 VGPRs

__device__ __forceinline__ u16 f2bfu_rn(float x) {
    u32 u = __builtin_bit_cast(u32, x);
    return (u16)((u + 0x8000u) >> 16);
}

// pack two f32 -> (bf16(hi)<<16)|bf16(lo), bit-identical to f2bfu_rn pairs.
__device__ __forceinline__ u32 pack_bf16(float lo, float hi) {
    u32 a = __builtin_bit_cast(u32, lo) + 0x8000u;
    u32 b = __builtin_bit_cast(u32, hi) + 0x8000u;
    return __builtin_amdgcn_perm(b, a, 0x07060302u);  // {b.b3,b.b2,a.b3,a.b2}
}

__device__ __forceinline__ void gl2lds16(const void* g, void* l) {
    __builtin_amdgcn_global_load_lds(
        (const __attribute__((address_space(1))) u32*)g,
        (__attribute__((address_space(3))) u32*)l, 16, 0, 0);
}

// ---------------------------------------------------------------------------
// fp32 -> bf16 conversion, 8 elems/thread
// ---------------------------------------------------------------------------
#define XN  8388608u    // 8192*1024
#define WN  1048576u    // 1024*1024
__global__ __launch_bounds__(256) void convert_bf16(
    const float* __restrict__ X,  const float* __restrict__ Wq,
    const float* __restrict__ Wk, const float* __restrict__ Wv,
    u16* __restrict__ Xb, u16* __restrict__ Wqb,
    u16* __restrict__ Wkb, u16* __restrict__ Wvb)
{
    size_t idx = ((size_t)blockIdx.x * 256 + threadIdx.x) * 8;
    const float* src; u16* dst; size_t off;
    if (idx < XN)                { src = X;  dst = Xb;  off = idx; }
    else if (idx < XN + WN)      { src = Wq; dst = Wqb; off = idx - XN; }
    else if (idx < XN + 2 * WN)  { src = Wk; dst = Wkb; off = idx - XN - WN; }
    else                         { src = Wv; dst = Wvb; off = idx - XN - 2 * WN; }
    float4 a = *(const float4*)(src + off);
    float4 b = *(const float4*)(src + off + 4);
    uint4 o;
    o.x = (u32)f2bfu_rn(a.x) | ((u32)f2bfu_rn(a.y) << 16);
    o.y = (u32)f2bfu_rn(a.z) | ((u32)f2bfu_rn(a.w) << 16);
    o.z = (u32)f2bfu_rn(b.x) | ((u32)f2bfu_rn(b.y) << 16);
    o.w = (u32)f2bfu_rn(b.z) | ((u32)f2bfu_rn(b.w) << 16);
    *(uint4*)(dst + off) = o;
}

// ---------------------------------------------------------------------------
// QKV projection GEMM: 128x128 tile, BK=32, ring-3 LDS (48KB), 4 waves (2x2),
// 1 barrier per K-tile, counted vmcnt(4).  Grid 512x3 (XCD-chunk swizzled),
// 3 blocks/CU, exactly 2 dispatch rounds.
// z=0: A=X, B=Wq -> Q = (X Wq^T + bq)*QSCALE -> [bh][s][hd]
// z=1: A=X, B=Wk -> K -> [bh][s][hd]
// z=2: A=Wv, B=X -> V^T -> [bh][hd][s]
// ---------------------------------------------------------------------------
#define QSCALE 0.18033688011112042f   // 0.125 * log2(e)

__global__ __launch_bounds__(256) void qkv_mfma8(
    const u16* __restrict__ Xb,
    const u16* __restrict__ Wqb, const u16* __restrict__ Wkb,
    const u16* __restrict__ Wvb,
    const float* __restrict__ bq, const float* __restrict__ bk,
    const float* __restrict__ bv,
    u16* __restrict__ Qb, u16* __restrict__ Kb, u16* __restrict__ Vtb)
{
    const int which = blockIdx.y;
    // 512 blocks -> 8 XCD chunks of 64 (bijective: 512 % 8 == 0)
    const int bxl = ((blockIdx.x & 7) << 6) | (blockIdx.x >> 3);

    const u16* Asrc; const u16* Bsrc; const float* bias; u16* Out;
    int m0, n0;
    if (which == 0)      { Asrc = Xb;  Bsrc = Wqb; bias = bq; Out = Qb;
                           m0 = (bxl >> 3) * 128; n0 = (bxl & 7) * 128; }
    else if (which == 1) { Asrc = Xb;  Bsrc = Wkb; bias = bk; Out = Kb;
                           m0 = (bxl >> 3) * 128; n0 = (bxl & 7) * 128; }
    else                 { Asrc = Wvb; Bsrc = Xb;  bias = bv; Out = Vtb;
                           m0 = (bxl & 7) * 128; n0 = (bxl >> 3) * 128; }

    __shared__ u16 As[3][128][32];   // 24 KB
    __shared__ u16 Bs[3][128][32];   // 24 KB

    const int t = threadIdx.x;
    const int wave = t >> 6, lane = t & 63;
    const int qd = lane >> 4, l15 = lane & 15;
    const int wm = wave >> 1, wn = wave & 1;   // 2 x 2 wave grid

    // stage K-tile tt (32-wide): 2 gl2lds/wave each for A and B (16 rows/issue)
    // LDS rows linear; source chunk pre-swizzled: g = (lane&3)^((r>>1)&3).
    auto STAGE_A = [&](int tt, int u) {        // u in {0,1}
        const int buf = tt % 3, k0 = tt * 32;
        const int rb = wave * 32 + u * 16;
        const int r  = rb + (lane >> 2);
        const int g  = (lane & 3) ^ ((r >> 1) & 3);
        gl2lds16(Asrc + (size_t)(m0 + r) * D_ + k0 + g * 8, &As[buf][rb][0]);
    };
    auto STAGE_B = [&](int tt, int u) {        // u in {0,1}
        const int buf = tt % 3, k0 = tt * 32;
        const int rb = wave * 32 + u * 16;
        const int r  = rb + (lane >> 2);
        const int g  = (lane & 3) ^ ((r >> 1) & 3);
        gl2lds16(Bsrc + (size_t)(n0 + r) * D_ + k0 + g * 8, &Bs[buf][rb][0]);
    };

    const f32x4 zero = {0.f, 0.f, 0.f, 0.f};
    f32x4 acc[4][4];
#pragma unroll
    for (int i = 0; i < 4; ++i)
#pragma unroll
        for (int j = 0; j < 4; ++j) acc[i][j] = zero;

    // ---- prologue: stage tiles 0 and 1; make tile 0 resident ----
    STAGE_A(0, 0); STAGE_A(0, 1); STAGE_B(0, 0); STAGE_B(0, 1);
    STAGE_A(1, 0); STAGE_A(1, 1); STAGE_B(1, 0); STAGE_B(1, 1);
    asm volatile("s_waitcnt vmcnt(4)" ::: "memory");
    __builtin_amdgcn_s_barrier();

    for (int tt = 0; tt < 32; ++tt) {
        const int buf = tt % 3;

        bf16x8 af[4], bfv[4];
#pragma unroll
        for (int nt = 0; nt < 4; ++nt) {
            const int row = wn * 64 + nt * 16 + l15;
            bfv[nt] = *(const bf16x8*)&Bs[buf][row][(qd ^ ((row >> 1) & 3)) * 8];
        }
#pragma unroll
        for (int mt = 0; mt < 4; ++mt) {
            const int row = wm * 64 + mt * 16 + l15;
            af[mt] = *(const bf16x8*)&As[buf][row][(qd ^ ((row >> 1) & 3)) * 8];
        }
        if (tt <= 29) {                 // stage tile tt+2 into (tt+2)%3
            const int t2 = tt + 2;      // overwrites (tt-1)%3: readers done
            STAGE_A(t2, 0); STAGE_A(t2, 1); STAGE_B(t2, 0); STAGE_B(t2, 1);
        }
        asm volatile("s_waitcnt lgkmcnt(0)" ::: "memory");
        __builtin_amdgcn_sched_barrier(0);
        __builtin_amdgcn_s_setprio(1);
#pragma unroll
        for (int mt = 0; mt < 4; ++mt)
#pragma unroll
            for (int nt = 0; nt < 4; ++nt)
                acc[mt][nt] = __builtin_amdgcn_mfma_f32_16x16x32_bf16(
                    af[mt], bfv[nt], acc[mt][nt], 0, 0, 0);
        __builtin_amdgcn_s_setprio(0);
        // boundary: retire tile tt+1's 4 issues (FIFO), keep tt+2's in flight
        if (tt <= 28) asm volatile("s_waitcnt vmcnt(4)" ::: "memory");
        else          asm volatile("s_waitcnt vmcnt(0)" ::: "memory");
        __builtin_amdgcn_s_barrier();
    }

    // ---- epilogue: C/D layout row = qd*4 + reg, col = l15 ----
    if (which < 2) {
#pragma unroll
        for (int nt = 0; nt < 4; ++nt) {
            int n = n0 + wn * 64 + nt * 16 + l15;      // feature
            float bv_ = bias[n];
            int h = n >> 6, hd = n & 63;
#pragma unroll
            for (int mt = 0; mt < 4; ++mt)
#pragma unroll
                for (int r = 0; r < 4; ++r) {
                    int m = m0 + wm * 64 + mt * 16 + qd * 4 + r;  // token
                    int bb = m >> 11, s = m & 2047;
                    float v = acc[mt][nt][r] + bv_;
                    if (which == 0) v *= QSCALE;
                    Out[(((size_t)(bb * H_ + h)) * S_ + s) * HD_ + hd] = f2bfu_rn(v);
                }
        }
    } else {
#pragma unroll
        for (int mt = 0; mt < 4; ++mt)
#pragma unroll
            for (int r = 0; r < 4; ++r) {
                int f = m0 + wm * 64 + mt * 16 + qd * 4 + r;      // feature
                float bv_ = bias[f];
                int h = f >> 6, hd = f & 63;
#pragma unroll
                for (int nt = 0; nt < 4; ++nt) {
                    int tok = n0 + wn * 64 + nt * 16 + l15;       // token
                    int bb = tok >> 11, s = tok & 2047;
                    float v = acc[mt][nt][r] + bv_;
                    Out[(((size_t)(bb * H_ + h)) * HD_ + hd) * S_ + s] = f2bfu_rn(v);
                }
            }
    }
}

// ---------------------------------------------------------------------------
// Split-K flash attention, deterministic (plain stores only).  [R17, kept]
// Grid 1-D 3072.  bid = xcd + 8*bhl + 64*rank -> bh = xcd*8 + bhl.
// rank->x remap: globally non-increasing tiles/block.
// Swapped QK^T (S^T = mfma(K,Q)); perm-pack P pairs -> uint2 LDS stores.
// Split issue points: K(t+1) after post-QK^T barrier, V(t+1)+probe after
// post-PV barrier; drains always covered by a compute phase.
// ---------------------------------------------------------------------------
__global__ __launch_bounds__(256) void attn_chunk(
    const u16* __restrict__ Qb, const u16* __restrict__ Kb,
    const u16* __restrict__ Vtb, const int* __restrict__ amask,
    float* __restrict__ Oout, float* __restrict__ Opart,
    float* __restrict__ L0, float* __restrict__ L1)
{
    const int bid = blockIdx.x;
    const int rank = bid >> 6;                      // 0..47
    int x;
    if (rank < 17)      x = rank;                   // 16-tile chunk0
    else if (rank == 17) x = 32;                    // 16-tile chunk1 (qt=31)
    else {
        int i = (rank - 18) >> 1;
        x = ((rank - 18) & 1) ? (33 + i) : (17 + i);
    }
    const int bh  = ((bid & 7) << 3) | ((bid >> 3) & 7);
    const int b = bh >> 4, h = bh & 15;
    int qt, jt0, jt1; bool second;
    if (x < 32) { qt = 31 - x; jt0 = 0;  jt1 = min(qt, 15); second = false; }
    else        { qt = 63 - x; jt0 = 16; jt1 = qt;          second = true;  }
    const int q0 = qt * 64;

    const int t = threadIdx.x;
    const int wave = t >> 6, lane = t & 63;
    const int qd = lane >> 4, l15 = lane & 15;

    __shared__ u16 Ks[64][64];     // [key][hd]  XOR-swizzled
    __shared__ u16 Vts[64][64];    // [hd][key]  XOR-swizzled
    __shared__ u16 Ps[64][72];     // [q][key]   padded (+8)

    const size_t base = (size_t)bh * S_ * HD_;
    const u16* Qg = Qb + base;
    const u16* Kg = Kb + base;
    const u16* Vg = Vtb + base;    // rows = hd, cols = s
    const int* am = amask + b * S_;

    bf16x8 qf[2];
    {
        const u16* qrow = Qg + (size_t)(q0 + wave * 16 + l15) * HD_;
        qf[0] = *(const bf16x8*)(qrow + qd * 8);
        qf[1] = *(const bf16x8*)(qrow + 32 + qd * 8);
    }
    bf16x8 onesf;
    {
        short v = (l15 == 0) ? (short)0x3F80 : (short)0;
        onesf = (bf16x8){v, v, v, v, v, v, v, v};
    }

    const f32x4 zero = {0.f, 0.f, 0.f, 0.f};
    f32x4 o[5];                    // 4 hd tiles + l tile
#pragma unroll
    for (int i = 0; i < 5; ++i) o[i] = zero;

    const int qloc = wave * 16 + l15;   // local q within the 64-row q tile
    u32* prow32 = (u32*)&Ps[qloc][0];   // this lane's P row (u32 view)

    // staging helpers (pre-swizzled source addresses, linear LDS rows)
    auto ISSUE_K = [&](int jt) {
        const int j0 = jt * 64;
#pragma unroll
        for (int i = 0; i < 2; ++i) {
            int r0  = (wave * 2 + i) * 8;
            int row = r0 + (lane >> 3);
            int g   = (lane & 7) ^ (row & 7);
            gl2lds16(Kg + (size_t)(j0 + row) * HD_ + g * 8, &Ks[r0][0]);
        }
    };
    auto ISSUE_V = [&](int jt) {
        const int j0 = jt * 64;
#pragma unroll
        for (int i = 0; i < 2; ++i) {
            int r0  = (wave * 2 + i) * 8;
            int row = r0 + (lane >> 3);
            int g   = (lane & 7) ^ (row & 7);
            gl2lds16(Vg + (size_t)row * S_ + j0 + g * 8, &Vts[r0][0]);
        }
    };

    // mask probe words for the CURRENT tile (loads issued one phase early;
    // __all deferred to point of use so the load latency hides)
    int am0, am1, am2, am3;
    auto PROBE = [&](int jt) {
        const int j0 = jt * 64;
        am0 = am[j0 + l15];      am1 = am[j0 + 16 + l15];
        am2 = am[j0 + 32 + l15]; am3 = am[j0 + 48 + l15];
    };

    // ---- prologue: stage tile jt0 ----
    ISSUE_K(jt0);
    ISSUE_V(jt0);
    PROBE(jt0);
    __syncthreads();               // drain K+V(jt0); all waves ready

    for (int jt = jt0; jt <= jt1; ++jt) {
        const int j0 = jt * 64;

        // ---- S^T = K Q^T  (swapped operands: A=K, B=Q) ----
        f32x4 sacc[4];
#pragma unroll
        for (int nt = 0; nt < 4; ++nt) sacc[nt] = zero;
        __builtin_amdgcn_s_setprio(1);
#pragma unroll
        for (int ks = 0; ks < 2; ++ks) {
#pragma unroll
            for (int nt = 0; nt < 4; ++nt) {
                int arow = nt * 16 + l15;
                int ap = (ks * 4 + qd) ^ (arow & 7);
                bf16x8 kf = *(const bf16x8*)&Ks[arow][ap * 8];
                sacc[nt] = __builtin_amdgcn_mfma_f32_16x16x32_bf16(
                    kf, qf[ks], sacc[nt], 0, 0, 0);
            }
        }
        __builtin_amdgcn_s_setprio(0);

        __syncthreads();           // (A) Ks readers done; drains V(jt)
        if (jt < jt1) ISSUE_K(jt + 1);   // flies under softmax+PV

        // ---- (mask) + causal + exp2 -> perm-pack pairs -> Ps row ----
        const bool fast = __all((int)((am0 != 0) & (am1 != 0) &
                                      (am2 != 0) & (am3 != 0)));
        const bool diag = (jt == qt);
#pragma unroll
        for (int nt = 0; nt < 4; ++nt) {
            float p[4];
#pragma unroll
            for (int r = 0; r < 4; ++r) {
                int kl = nt * 16 + qd * 4 + r;       // local key
                float s = sacc[nt][r];
                if (!fast) {                         // rare: some key masked
                    if (am[j0 + kl] == 0) s = -1e30f;
                }
                if (diag && kl > qloc) s = -1e30f;
                p[r] = __builtin_amdgcn_exp2f(s);
            }
            uint2 w;
            w.x = pack_bf16(p[0], p[1]);
            w.y = pack_bf16(p[2], p[3]);
            *(uint2*)&prow32[nt * 8 + qd * 2] = w;   // keys nt*16+qd*4 .. +3
        }

        // ---- O += P V ; l += P ones (same-wave LDS rows, no barrier) ----
        __builtin_amdgcn_s_setprio(1);
#pragma unroll
        for (int ks = 0; ks < 2; ++ks) {
            int arow = wave * 16 + l15;
            bf16x8 pf = *(const bf16x8*)&Ps[arow][ks * 32 + qd * 8];
#pragma unroll
            for (int nt = 0; nt < 4; ++nt) {
                int brow = nt * 16 + l15;
                int bp = (ks * 4 + qd) ^ (brow & 7);
                bf16x8 vf = *(const bf16x8*)&Vts[brow][bp * 8];
                o[nt] = __builtin_amdgcn_mfma_f32_16x16x32_bf16(
                    pf, vf, o[nt], 0, 0, 0);
            }
            o[4] = __builtin_amdgcn_mfma_f32_16x16x32_bf16(
                pf, onesf, o[4], 0, 0, 0);
        }
        __builtin_amdgcn_s_setprio(0);

        if (jt < jt1) {
            __syncthreads();       // (B) Vts readers done; drains K(jt+1)
            ISSUE_V(jt + 1);       // flies under next QK^T
            PROBE(jt + 1);         // loads issued; __all deferred
        }
    }

    // ---- epilogue: plain stores (each destination written by ONE block) ----
    if (!second) {
        if (qt <= 15) {
#pragma unroll
            for (int r = 0; r < 4; ++r) {
                float l = __shfl(o[4][r], lane & 48);
                float inv = 1.0f / l;
                int q = q0 + wave * 16 + qd * 4 + r;
                float* op = Oout + ((size_t)(b * S_ + q)) * D_ + h * HD_;
#pragma unroll
                for (int nt = 0; nt < 4; ++nt)
                    op[nt * 16 + l15] = o[nt][r] * inv;
            }
        } else {
#pragma unroll
            for (int r = 0; r < 4; ++r) {
                int q = q0 + wave * 16 + qd * 4 + r;
                float* op = Oout + ((size_t)(b * S_ + q)) * D_ + h * HD_;
#pragma unroll
                for (int nt = 0; nt < 4; ++nt)
                    op[nt * 16 + l15] = o[nt][r];
                if (l15 == 0) L0[(size_t)bh * S_ + q] = o[4][r];
            }
        }
    } else {
#pragma unroll
        for (int r = 0; r < 4; ++r) {
            int q = q0 + wave * 16 + qd * 4 + r;
            int sh = q - 1024;
            float* op = Opart + ((size_t)bh * 1024 + sh) * HD_;
#pragma unroll
            for (int nt = 0; nt < 4; ++nt)
                op[nt * 16 + l15] = o[nt][r];
            if (l15 == 0) L1[(size_t)bh * 1024 + sh] = o[4][r];
        }
    }
}

// ---------------------------------------------------------------------------
// combine: rows s >= 1024 only.  out = (out + Opart) / (L0 + L1).
// ---------------------------------------------------------------------------
__global__ __launch_bounds__(256) void combine(
    float* __restrict__ out, const float* __restrict__ Opart,
    const float* __restrict__ L0, const float* __restrict__ L1)
{
    size_t i = ((size_t)blockIdx.x * 256 + threadIdx.x) * 4;
    int d  = (int)(i & (D_ - 1));
    int bs = (int)(i >> 10);          // b*1024 + (s-1024)
    int b  = bs >> 10, sh = bs & 1023;
    int s  = sh + 1024;
    int h  = d >> 6;
    int bh = b * H_ + h;
    float l = L0[(size_t)bh * S_ + s] + L1[(size_t)bh * 1024 + sh];
    float inv = 1.0f / l;
    float* op = out + ((size_t)(b * S_ + s)) * D_ + d;
    const float* pp = Opart + ((size_t)bh * 1024 + sh) * HD_ + (d & 63);
    float4 v = *(float4*)op;
    float4 p = *(const float4*)pp;
    v.x = (v.x + p.x) * inv; v.y = (v.y + p.y) * inv;
    v.z = (v.z + p.z) * inv; v.w = (v.w + p.w) * inv;
    *(float4*)op = v;
}

// ---------------------------------------------------------------------------
extern "C" void kernel_launch(void* const* d_in, const int* in_sizes, int n_in,
                              void* d_out, int out_size, void* d_ws, size_t ws_size,
                              hipStream_t stream) {
    (void)in_sizes; (void)n_in; (void)out_size; (void)ws_size;
    const float* X    = (const float*)d_in[0];
    const int*   mask = (const int*)d_in[1];
    const float* Wq   = (const float*)d_in[2];
    const float* bq   = (const float*)d_in[3];
    const float* Wk   = (const float*)d_in[4];
    const float* bk   = (const float*)d_in[5];
    const float* Wv   = (const float*)d_in[6];
    const float* bv   = (const float*)d_in[7];
    float* out = (float*)d_out;

    u16* Xb  = (u16*)d_ws;                 // 8192x1024 bf16
    u16* Wqb = Xb  + XN;                   // 1024x1024 bf16
    u16* Wkb = Wqb + WN;
    u16* Wvb = Wkb + WN;
    u16* Qb  = Wvb + WN;                   // [bh][s][hd]  (pre-scaled by QSCALE)
    u16* Kb  = Qb  + XN;
    u16* Vtb = Kb  + XN;                   // [bh][hd][s]
    float* Opart = (float*)(Vtb + XN);     // [bh][1024][64] fp32 (16.8 MB)
    float* L0 = Opart + (size_t)64 * 1024 * 64;   // [bh][2048]
    float* L1 = L0 + (size_t)64 * 2048;           // [bh][1024]

    convert_bf16<<<(XN + 3 * WN) / (256 * 8), 256, 0, stream>>>(
        X, Wq, Wk, Wv, Xb, Wqb, Wkb, Wvb);
    qkv_mfma8<<<dim3(512, 3), 256, 0, stream>>>(
        Xb, Wqb, Wkb, Wvb, bq, bk, bv, Qb, Kb, Vtb);
    attn_chunk<<<dim3(3072), 256, 0, stream>>>(
        Qb, Kb, Vtb, mask, out, Opart, L0, L1);
    combine<<<(B_ * 1024 * D_ / 4) / 256, 256, 0, stream>>>(out, Opart, L0, L1);
}